// Round 3
// baseline (1662.355 us; speedup 1.0000x reference)
//
#include <hip/hip_runtime.h>
#include <stdint.h>

#define BS 32
#define SEQ 48
#define VOCAB 32529
#define HD 512
#define IMG_F 4096
#define EPS 1e-5f
#define NPAD16 2040  // padded n16 tiles for Wout (2040*16 = 32640 >= 32529)

typedef __attribute__((ext_vector_type(8))) short short8;
typedef __attribute__((ext_vector_type(4))) float f32x4;

#define MFMA(a, b, c) __builtin_amdgcn_mfma_f32_16x16x32_bf16(a, b, c, 0, 0, 0)

static __device__ __forceinline__ unsigned short f2bf(float v) {
  union { float f; unsigned u; } c; c.f = v;
  unsigned r = (c.u + 0x7FFFu + ((c.u >> 16) & 1u)) >> 16;
  return (unsigned short)r;
}
static __device__ __forceinline__ float bf2f(unsigned short h) {
  union { unsigned u; float f; } c; c.u = ((unsigned)h) << 16; return c.f;
}
static __device__ __forceinline__ float sigf(float x) {
  x = fminf(fmaxf(x, -30.f), 30.f);
  return 1.f / (1.f + __expf(-x));
}
static __device__ __forceinline__ float tanh_(float x) {
  float t = __expf(fminf(fmaxf(2.f * x, -30.f), 30.f));
  return (t - 1.f) / (t + 1.f);
}

// device-scope grid barrier (all blocks guaranteed co-resident: 64 blocks on 256 CUs)
static __device__ __forceinline__ void gbar(unsigned* ctr, unsigned target) {
  __syncthreads();
  if (threadIdx.x == 0) {
    __threadfence();  // release: make prior writes visible device-wide
    atomicAdd(ctr, 1u);
    while (atomicAdd(ctr, 0u) < target) __builtin_amdgcn_s_sleep(2);
  }
  __syncthreads();
  __threadfence();  // acquire: invalidate stale cached lines
}

// ---------- gather xe = emb[x], split bf16 hi/lo; rows m = t*32+b ----------
__global__ __launch_bounds__(256) void k_gather(const float* __restrict__ emb,
                                                const int* __restrict__ x,
                                                unsigned short* __restrict__ xh,
                                                unsigned short* __restrict__ xl) {
  int idx = blockIdx.x * 256 + threadIdx.x;  // 1536*128 float4s
  int m = idx >> 7;
  int k4 = (idx & 127) << 2;
  int t = m >> 5, b = m & 31;
  int row = x[b * SEQ + t];
  float4 v = *(const float4*)(emb + (size_t)row * HD + k4);
  float vv[4] = {v.x, v.y, v.z, v.w};
  unsigned short h_[4], l_[4];
#pragma unroll
  for (int i = 0; i < 4; ++i) {
    h_[i] = f2bf(vv[i]);
    l_[i] = f2bf(vv[i] - bf2f(h_[i]));
  }
  ushort4 hq = {h_[0], h_[1], h_[2], h_[3]};
  ushort4 lq = {l_[0], l_[1], l_[2], l_[3]};
  *(ushort4*)(xh + (size_t)m * HD + k4) = hq;
  *(ushort4*)(xl + (size_t)m * HD + k4) = lq;
}

// ---------- pack [512][2048] fp32 -> split-bf16 B-fragment order ----------
__global__ __launch_bounds__(256) void k_pack(const float* __restrict__ W,
                                              unsigned short* __restrict__ Ph,
                                              unsigned short* __restrict__ Pl) {
  int f = blockIdx.x * 256 + threadIdx.x;  // 131072 frag-lanes
  int lane = f & 63;
  int kk = (f >> 6) & 15;
  int n16 = f >> 10;
  int c = n16 * 16 + (lane & 15);
  int k0 = kk * 32 + (lane >> 4) * 8;
  short8 oh, ol;
#pragma unroll
  for (int i = 0; i < 8; ++i) {
    float v = W[(size_t)(k0 + i) * 2048 + c];
    unsigned short hb = f2bf(v);
    oh[i] = (short)hb;
    ol[i] = (short)f2bf(v - bf2f(hb));
  }
  *(short8*)(Ph + (size_t)f * 8) = oh;
  *(short8*)(Pl + (size_t)f * 8) = ol;
}

// ---------- pack Wout [512][32529] fp32 -> plain bf16 B-frags, zero-pad to 32640 ----------
__global__ __launch_bounds__(256) void k_packw(const float* __restrict__ W,
                                               unsigned short* __restrict__ P) {
  int f = blockIdx.x * 256 + threadIdx.x;  // NPAD16*16*64 = 2088960 frag-lanes
  int lane = f & 63;
  int kk = (f >> 6) & 15;
  int n16 = f >> 10;
  int c = n16 * 16 + (lane & 15);
  int k0 = kk * 32 + (lane >> 4) * 8;
  short8 o;
#pragma unroll
  for (int i = 0; i < 8; ++i) {
    float v = (c < VOCAB) ? W[(size_t)(k0 + i) * VOCAB + c] : 0.f;
    o[i] = (short)f2bf(v);
  }
  *(short8*)(P + (size_t)f * 8) = o;
}

// ---------- CNN layer: out = relu(BN(in @ W^T)); bias cancels in training BN ----------
template <int INF, int OUTF>
__global__ __launch_bounds__(256) void k_cnn(const float* __restrict__ in,
                                             const float* __restrict__ W,
                                             const float* __restrict__ gamma,
                                             const float* __restrict__ beta,
                                             float* __restrict__ out) {
  int tid = threadIdx.x;
  int b = tid & 31;
  int o = blockIdx.x * 8 + (tid >> 5);
  const float4* ip = (const float4*)(in + (size_t)b * INF);
  const float4* wp = (const float4*)(W + (size_t)o * INF);
  float a0 = 0, a1 = 0, a2 = 0, a3 = 0;
#pragma unroll 8
  for (int k = 0; k < INF / 4; ++k) {
    float4 a = ip[k], w = wp[k];
    a0 = fmaf(a.x, w.x, a0);
    a1 = fmaf(a.y, w.y, a1);
    a2 = fmaf(a.z, w.z, a2);
    a3 = fmaf(a.w, w.w, a3);
  }
  float pre = (a0 + a1) + (a2 + a3);
  float s = pre, q = pre * pre;
#pragma unroll
  for (int mk = 16; mk >= 1; mk >>= 1) {
    s += __shfl_xor(s, mk);
    q += __shfl_xor(q, mk);
  }
  float mu = s * (1.f / 32.f);
  float var = q * (1.f / 32.f) - mu * mu;
  float y = gamma[o] * (pre - mu) * rsqrtf(var + EPS) + beta[o];
  out[(size_t)b * OUTF + o] = fmaxf(y, 0.f);
}

// ---------- xU GEMM: zx[m][0:2048] = xe[m] @ U + bg (split-bf16, 3 terms) ----------
__global__ __launch_bounds__(256) void k_xu(const unsigned short* __restrict__ xh,
                                            const unsigned short* __restrict__ xl,
                                            const unsigned short* __restrict__ Uh,
                                            const unsigned short* __restrict__ Ul,
                                            const float* __restrict__ bg,
                                            float* __restrict__ zx) {
  int mb = blockIdx.x;  // 48
  int nb = blockIdx.y;  // 16
  int w = threadIdx.x >> 6, l = threadIdx.x & 63;
  int lr = l & 15, lg = l >> 4;
  f32x4 acc[2][2] = {};
#pragma unroll 2
  for (int kk = 0; kk < 16; ++kk) {
    short8 ah[2], al[2];
#pragma unroll
    for (int m = 0; m < 2; ++m) {
      size_t ao = (size_t)(mb * 32 + m * 16 + lr) * HD + kk * 32 + lg * 8;
      ah[m] = *(const short8*)(xh + ao);
      al[m] = *(const short8*)(xl + ao);
    }
#pragma unroll
    for (int n = 0; n < 2; ++n) {
      int n16 = nb * 8 + w * 2 + n;
      size_t bo = ((size_t)(n16 * 16 + kk) * 64 + l) * 8;
      short8 bh = *(const short8*)(Uh + bo);
      short8 bl = *(const short8*)(Ul + bo);
#pragma unroll
      for (int m = 0; m < 2; ++m) {
        acc[m][n] = MFMA(ah[m], bh, acc[m][n]);
        acc[m][n] = MFMA(al[m], bh, acc[m][n]);
        acc[m][n] = MFMA(ah[m], bl, acc[m][n]);
      }
    }
  }
#pragma unroll
  for (int m = 0; m < 2; ++m)
#pragma unroll
    for (int n = 0; n < 2; ++n) {
      int col = (nb * 8 + w * 2 + n) * 16 + lr;
#pragma unroll
      for (int r = 0; r < 4; ++r) {
        int row = mb * 32 + m * 16 + lg * 4 + r;
        zx[(size_t)row * 2048 + col] = acc[m][n][r] + bg[col];
      }
    }
}

// ---------- persistent LSTM: image step + 48 scan steps, grid barrier between ----------
__global__ __launch_bounds__(256, 1) void k_lstm(
    const float* __restrict__ feat, const float* __restrict__ bg,
    const float* __restrict__ zx,
    const unsigned short* __restrict__ Vh, const unsigned short* __restrict__ Vl,
    unsigned short* __restrict__ hAh, unsigned short* __restrict__ hAl,
    unsigned short* __restrict__ hBh, unsigned short* __restrict__ hBl,
    unsigned short* __restrict__ hsb, float* __restrict__ hout,
    float* __restrict__ cout_, unsigned* __restrict__ barctr) {
  __shared__ float zsh[4][16][17];
  int blk = blockIdx.x;           // 64 blocks: (mh, nb)
  int mh = blk >> 5, nb = blk & 31;
  int tid = threadIdx.x;
  int w = tid >> 6, l = tid & 63, lr = l & 15, lg = l >> 4;
  int n16 = w * 32 + nb;          // wave = gate
  // V fragments live in registers for the whole recurrence (32x short8 = 128 VGPR)
  short8 vh[16], vl[16];
#pragma unroll
  for (int kk = 0; kk < 16; ++kk) {
    size_t bo = ((size_t)(n16 * 16 + kk) * 64 + l) * 8;
    vh[kk] = *(const short8*)(Vh + bo);
    vl[kk] = *(const short8*)(Vl + bo);
  }
  int bl_ = tid >> 4, j = tid & 15;
  int b = mh * 16 + bl_, col = nb * 16 + j;
  int ci = b * HD + col;
  // image step (h=0, c=0): z = feat broadcast to all gates + bg
  float fv = feat[ci];
  float c = sigf(fv + bg[col]) * tanh_(fv + bg[1024 + col]);
  float h = sigf(fv + bg[1536 + col]) * tanh_(c);
  {
    unsigned short hb_ = f2bf(h);
    hAh[ci] = hb_;
    hAl[ci] = f2bf(h - bf2f(hb_));
  }
  gbar(barctr, 64u);
  for (int t = 0; t < 48; ++t) {
    const unsigned short* ih = (t & 1) ? hBh : hAh;
    const unsigned short* il = (t & 1) ? hBl : hAl;
    unsigned short* oh = (t & 1) ? hAh : hBh;
    unsigned short* ol = (t & 1) ? hAl : hBl;
    // prefetch zx row early (hides L3 latency under MFMA)
    const float* zr = zx + ((size_t)t * 32 + b) * 2048 + col;
    float z0p = zr[0], z1p = zr[512], z2p = zr[1024], z3p = zr[1536];
    // z-tile = h @ V for this (gate, nb) via split-bf16; 2 acc chains
    f32x4 acc0 = {}, acc1 = {};
#pragma unroll
    for (int kk = 0; kk < 16; ++kk) {
      size_t ao = (size_t)(mh * 16 + lr) * HD + kk * 32 + lg * 8;
      short8 ah = *(const short8*)(ih + ao);
      short8 al = *(const short8*)(il + ao);
      if (kk & 1) {
        acc1 = MFMA(ah, vh[kk], acc1);
        acc1 = MFMA(al, vh[kk], acc1);
        acc1 = MFMA(ah, vl[kk], acc1);
      } else {
        acc0 = MFMA(ah, vh[kk], acc0);
        acc0 = MFMA(al, vh[kk], acc0);
        acc0 = MFMA(ah, vl[kk], acc0);
      }
    }
    f32x4 acc;
#pragma unroll
    for (int r = 0; r < 4; ++r) acc[r] = acc0[r] + acc1[r];
#pragma unroll
    for (int r = 0; r < 4; ++r) zsh[w][lg * 4 + r][lr] = acc[r];
    __syncthreads();
    float zi = zsh[0][bl_][j] + z0p;
    float zf = zsh[1][bl_][j] + z1p;
    float zg = zsh[2][bl_][j] + z2p;
    float zo = zsh[3][bl_][j] + z3p;
    c = sigf(zf) * c + sigf(zi) * tanh_(zg);
    h = sigf(zo) * tanh_(c);
    unsigned short hb2 = f2bf(h);
    oh[ci] = hb2;
    ol[ci] = f2bf(h - bf2f(hb2));
    hsb[((size_t)b * SEQ + t) * HD + col] = hb2;
    if (t < 47) gbar(barctr, 64u * (t + 2));
  }
  hout[ci] = h;
  cout_[ci] = c;
}

// ---------- output GEMM + softmax, two-pass recompute ----------
// MODE 0: rowsum of exp(logits); MODE 1: write probs = exp(logits)/rowsum
template <int MODE>
__global__ __launch_bounds__(256) void k_out(const unsigned short* __restrict__ A,
                                             const unsigned short* __restrict__ B,
                                             const float* __restrict__ bout,
                                             float* __restrict__ rowsum,
                                             float* __restrict__ dst) {
  int nb = blockIdx.x;  // 0..254 (n-tile 128)
  int mb = blockIdx.y;  // 0..11  (m-tile 128)
  int tid = threadIdx.x;
  int w = tid >> 6, l = tid & 63, lr = l & 15, lg = l >> 4;
  int wr = w >> 1, wc = w & 1;  // 2x2 wave grid, each wave 64x64
  int mrow0 = mb * 128 + wr * 64;
  int n16_0 = nb * 8 + wc * 4;
  f32x4 acc[4][4] = {};
#pragma unroll 2
  for (int kk = 0; kk < 16; ++kk) {
    short8 a[4], bf[4];
#pragma unroll
    for (int mt = 0; mt < 4; ++mt)
      a[mt] = *(const short8*)(A + (size_t)(mrow0 + mt * 16 + lr) * HD + kk * 32 + lg * 8);
#pragma unroll
    for (int nt = 0; nt < 4; ++nt)
      bf[nt] = *(const short8*)(B + ((size_t)((n16_0 + nt) * 16 + kk) * 64 + l) * 8);
#pragma unroll
    for (int nt = 0; nt < 4; ++nt)
#pragma unroll
      for (int mt = 0; mt < 4; ++mt) acc[mt][nt] = MFMA(a[mt], bf[nt], acc[mt][nt]);
  }
#pragma unroll
  for (int mt = 0; mt < 4; ++mt) {
#pragma unroll
    for (int r = 0; r < 4; ++r) {
      int row = mrow0 + mt * 16 + lg * 4 + r;
      float inv = 1.f;
      if (MODE == 1) inv = 1.f / rowsum[row];
      float s = 0.f;
#pragma unroll
      for (int nt = 0; nt < 4; ++nt) {
        int col = (n16_0 + nt) * 16 + lr;
        bool valid = col < VOCAB;
        float e = __expf(acc[mt][nt][r] + (valid ? bout[col] : 0.f));
        if (MODE == 0) {
          s += valid ? e : 0.f;
        } else {
          if (valid) dst[(size_t)row * VOCAB + col] = e * inv;
        }
      }
      if (MODE == 0) {
        s += __shfl_xor(s, 1);
        s += __shfl_xor(s, 2);
        s += __shfl_xor(s, 4);
        s += __shfl_xor(s, 8);
        if (lr == 0) atomicAdd(&rowsum[row], s);
      }
    }
  }
}

extern "C" void kernel_launch(void* const* d_in, const int* in_sizes, int n_in,
                              void* d_out, int out_size, void* d_ws, size_t ws_size,
                              hipStream_t stream) {
  const float* img  = (const float*)d_in[0];
  const int*   x    = (const int*)d_in[1];
  const float* w1   = (const float*)d_in[2];
  const float* g1   = (const float*)d_in[4];
  const float* be1  = (const float*)d_in[5];
  const float* w2   = (const float*)d_in[6];
  const float* g2   = (const float*)d_in[8];
  const float* be2  = (const float*)d_in[9];
  const float* w3   = (const float*)d_in[10];
  const float* g3   = (const float*)d_in[12];
  const float* be3  = (const float*)d_in[13];
  const float* U    = (const float*)d_in[14];
  const float* V    = (const float*)d_in[15];
  const float* bg   = (const float*)d_in[16];
  const float* emb  = (const float*)d_in[17];
  const float* Wout = (const float*)d_in[18];
  const float* bout = (const float*)d_in[19];

  char* ws = (char*)d_ws;
  size_t off = 0;
  auto alloc = [&](size_t bytes) -> void* {
    void* p = ws + off;
    off = (off + bytes + 255) & ~(size_t)255;
    return p;
  };
  float* zx = (float*)alloc((size_t)48 * 32 * 2048 * 4);
  unsigned short* xh = (unsigned short*)alloc((size_t)1536 * 512 * 2);
  unsigned short* xl = (unsigned short*)alloc((size_t)1536 * 512 * 2);
  unsigned short* Uh = (unsigned short*)alloc((size_t)512 * 2048 * 2);
  unsigned short* Ul = (unsigned short*)alloc((size_t)512 * 2048 * 2);
  unsigned short* Vh = (unsigned short*)alloc((size_t)512 * 2048 * 2);
  unsigned short* Vl = (unsigned short*)alloc((size_t)512 * 2048 * 2);
  unsigned short* Wp = (unsigned short*)alloc((size_t)NPAD16 * 16 * 64 * 8 * 2);  // 33.4 MB
  unsigned short* hAh = (unsigned short*)alloc(32 * 512 * 2);
  unsigned short* hAl = (unsigned short*)alloc(32 * 512 * 2);
  unsigned short* hBh = (unsigned short*)alloc(32 * 512 * 2);
  unsigned short* hBl = (unsigned short*)alloc(32 * 512 * 2);
  unsigned short* hsb = (unsigned short*)alloc((size_t)1536 * 512 * 2);
  float* feat = (float*)alloc(32 * 512 * 4);
  float* h1 = (float*)alloc(32 * 2048 * 4);
  float* h2 = (float*)alloc(32 * 1024 * 4);
  float* rowsum = (float*)alloc(1536 * 4);
  unsigned* barctr = (unsigned*)alloc(256);

  float* out = (float*)d_out;
  float* hout = out + 49964544;          // [32][512] final h
  float* cout_ = out + 49964544 + 16384;  // [32][512] final c

  k_gather<<<dim3(768), dim3(256), 0, stream>>>(emb, x, xh, xl);
  k_pack<<<dim3(512), dim3(256), 0, stream>>>(U, Uh, Ul);
  k_pack<<<dim3(512), dim3(256), 0, stream>>>(V, Vh, Vl);
  k_packw<<<dim3(8160), dim3(256), 0, stream>>>(Wout, Wp);
  k_cnn<4096, 2048><<<dim3(256), dim3(256), 0, stream>>>(img, w1, g1, be1, h1);
  k_cnn<2048, 1024><<<dim3(128), dim3(256), 0, stream>>>(h1, w2, g2, be2, h2);
  k_cnn<1024, 512><<<dim3(64), dim3(256), 0, stream>>>(h2, w3, g3, be3, feat);
  k_xu<<<dim3(48, 16), dim3(256), 0, stream>>>(xh, xl, Uh, Ul, bg, zx);
  hipMemsetAsync(barctr, 0, 256, stream);
  hipMemsetAsync(rowsum, 0, 1536 * 4, stream);
  k_lstm<<<dim3(64), dim3(256), 0, stream>>>(feat, bg, zx, Vh, Vl, hAh, hAl, hBh, hBl,
                                             hsb, hout, cout_, barctr);
  k_out<0><<<dim3(255, 12), dim3(256), 0, stream>>>(hsb, Wp, bout, rowsum, out);
  k_out<1><<<dim3(255, 12), dim3(256), 0, stream>>>(hsb, Wp, bout, rowsum, out);
}

// Round 4
// 1561.346 us; speedup vs baseline: 1.0647x; 1.0647x over previous
//
#include <hip/hip_runtime.h>
#include <stdint.h>

#define BS 32
#define SEQ 48
#define VOCAB 32529
#define HD 512
#define IMG_F 4096
#define EPS 1e-5f
#define NPAD16 2048  // padded n16 tiles for Wout (2048*16 = 32768 >= 32529)

typedef __attribute__((ext_vector_type(8))) short short8;
typedef __attribute__((ext_vector_type(4))) float f32x4;

#define MFMA(a, b, c) __builtin_amdgcn_mfma_f32_16x16x32_bf16(a, b, c, 0, 0, 0)

static __device__ __forceinline__ unsigned short f2bf(float v) {
  union { float f; unsigned u; } c; c.f = v;
  unsigned r = (c.u + 0x7FFFu + ((c.u >> 16) & 1u)) >> 16;
  return (unsigned short)r;
}
static __device__ __forceinline__ float bf2f(unsigned short h) {
  union { unsigned u; float f; } c; c.u = ((unsigned)h) << 16; return c.f;
}
static __device__ __forceinline__ float sigf(float x) {
  x = fminf(fmaxf(x, -30.f), 30.f);
  return 1.f / (1.f + __expf(-x));
}
static __device__ __forceinline__ float tanh_(float x) {
  float t = __expf(fminf(fmaxf(2.f * x, -30.f), 30.f));
  return (t - 1.f) / (t + 1.f);
}

// ---------- gather xe = emb[x], split bf16 hi/lo; rows m = t*32+b ----------
__global__ __launch_bounds__(256) void k_gather(const float* __restrict__ emb,
                                                const int* __restrict__ x,
                                                unsigned short* __restrict__ xh,
                                                unsigned short* __restrict__ xl) {
  int idx = blockIdx.x * 256 + threadIdx.x;  // 1536*128 float4s
  int m = idx >> 7;
  int k4 = (idx & 127) << 2;
  int t = m >> 5, b = m & 31;
  int row = x[b * SEQ + t];
  float4 v = *(const float4*)(emb + (size_t)row * HD + k4);
  float vv[4] = {v.x, v.y, v.z, v.w};
  unsigned short h_[4], l_[4];
#pragma unroll
  for (int i = 0; i < 4; ++i) {
    h_[i] = f2bf(vv[i]);
    l_[i] = f2bf(vv[i] - bf2f(h_[i]));
  }
  ushort4 hq = {h_[0], h_[1], h_[2], h_[3]};
  ushort4 lq = {l_[0], l_[1], l_[2], l_[3]};
  *(ushort4*)(xh + (size_t)m * HD + k4) = hq;
  *(ushort4*)(xl + (size_t)m * HD + k4) = lq;
}

// ---------- pack [512][2048] fp32 -> split-bf16 B-fragment order ----------
__global__ __launch_bounds__(256) void k_pack(const float* __restrict__ W,
                                              unsigned short* __restrict__ Ph,
                                              unsigned short* __restrict__ Pl) {
  int f = blockIdx.x * 256 + threadIdx.x;  // 131072 frag-lanes
  int lane = f & 63;
  int kk = (f >> 6) & 15;
  int n16 = f >> 10;
  int c = n16 * 16 + (lane & 15);
  int k0 = kk * 32 + (lane >> 4) * 8;
  short8 oh, ol;
#pragma unroll
  for (int i = 0; i < 8; ++i) {
    float v = W[(size_t)(k0 + i) * 2048 + c];
    unsigned short hb = f2bf(v);
    oh[i] = (short)hb;
    ol[i] = (short)f2bf(v - bf2f(hb));
  }
  *(short8*)(Ph + (size_t)f * 8) = oh;
  *(short8*)(Pl + (size_t)f * 8) = ol;
}

// ---------- pack Wout [512][32529] fp32 -> plain bf16 B-frags, zero-pad to 32768 ----------
__global__ __launch_bounds__(256) void k_packw(const float* __restrict__ W,
                                               unsigned short* __restrict__ P) {
  int f = blockIdx.x * 256 + threadIdx.x;  // NPAD16*16*64 frag-lanes
  int lane = f & 63;
  int kk = (f >> 6) & 15;
  int n16 = f >> 10;
  int c = n16 * 16 + (lane & 15);
  int k0 = kk * 32 + (lane >> 4) * 8;
  short8 o;
#pragma unroll
  for (int i = 0; i < 8; ++i) {
    float v = (c < VOCAB) ? W[(size_t)(k0 + i) * VOCAB + c] : 0.f;
    o[i] = (short)f2bf(v);
  }
  *(short8*)(P + (size_t)f * 8) = o;
}

// ---------- pack hsb [1536][512] bf16 -> A-fragment order ----------
__global__ __launch_bounds__(256) void k_packa(const unsigned short* __restrict__ hsb,
                                               unsigned short* __restrict__ Af) {
  int f = blockIdx.x * 256 + threadIdx.x;  // 96*16*64 = 98304 frag-lanes
  int lane = f & 63;
  int kk = (f >> 6) & 15;
  int m16 = f >> 10;
  int row = m16 * 16 + (lane & 15);
  int k0 = kk * 32 + (lane >> 4) * 8;
  short8 v = *(const short8*)(hsb + (size_t)row * HD + k0);
  *(short8*)(Af + (size_t)f * 8) = v;
}

// ---------- CNN layer: out = relu(BN(in @ W^T)); bias cancels in training BN ----------
template <int INF, int OUTF>
__global__ __launch_bounds__(256) void k_cnn(const float* __restrict__ in,
                                             const float* __restrict__ W,
                                             const float* __restrict__ gamma,
                                             const float* __restrict__ beta,
                                             float* __restrict__ out) {
  int tid = threadIdx.x;
  int b = tid & 31;
  int o = blockIdx.x * 8 + (tid >> 5);
  const float4* ip = (const float4*)(in + (size_t)b * INF);
  const float4* wp = (const float4*)(W + (size_t)o * INF);
  float a0 = 0, a1 = 0, a2 = 0, a3 = 0;
#pragma unroll 8
  for (int k = 0; k < INF / 4; ++k) {
    float4 a = ip[k], w = wp[k];
    a0 = fmaf(a.x, w.x, a0);
    a1 = fmaf(a.y, w.y, a1);
    a2 = fmaf(a.z, w.z, a2);
    a3 = fmaf(a.w, w.w, a3);
  }
  float pre = (a0 + a1) + (a2 + a3);
  float s = pre, q = pre * pre;
#pragma unroll
  for (int mk = 16; mk >= 1; mk >>= 1) {
    s += __shfl_xor(s, mk);
    q += __shfl_xor(q, mk);
  }
  float mu = s * (1.f / 32.f);
  float var = q * (1.f / 32.f) - mu * mu;
  float y = gamma[o] * (pre - mu) * rsqrtf(var + EPS) + beta[o];
  out[(size_t)b * OUTF + o] = fmaxf(y, 0.f);
}

// ---------- xU GEMM: zx[m][0:2048] = xe[m] @ U + bg (split-bf16, 3 terms) ----------
__global__ __launch_bounds__(256) void k_xu(const unsigned short* __restrict__ xh,
                                            const unsigned short* __restrict__ xl,
                                            const unsigned short* __restrict__ Uh,
                                            const unsigned short* __restrict__ Ul,
                                            const float* __restrict__ bg,
                                            float* __restrict__ zx) {
  int mb = blockIdx.x;  // 48
  int nb = blockIdx.y;  // 16
  int w = threadIdx.x >> 6, l = threadIdx.x & 63;
  int lr = l & 15, lg = l >> 4;
  f32x4 acc[2][2] = {};
#pragma unroll 2
  for (int kk = 0; kk < 16; ++kk) {
    short8 ah[2], al[2];
#pragma unroll
    for (int m = 0; m < 2; ++m) {
      size_t ao = (size_t)(mb * 32 + m * 16 + lr) * HD + kk * 32 + lg * 8;
      ah[m] = *(const short8*)(xh + ao);
      al[m] = *(const short8*)(xl + ao);
    }
#pragma unroll
    for (int n = 0; n < 2; ++n) {
      int n16 = nb * 8 + w * 2 + n;
      size_t bo = ((size_t)(n16 * 16 + kk) * 64 + l) * 8;
      short8 bh = *(const short8*)(Uh + bo);
      short8 bl = *(const short8*)(Ul + bo);
#pragma unroll
      for (int m = 0; m < 2; ++m) {
        acc[m][n] = MFMA(ah[m], bh, acc[m][n]);
        acc[m][n] = MFMA(al[m], bh, acc[m][n]);
        acc[m][n] = MFMA(ah[m], bl, acc[m][n]);
      }
    }
  }
#pragma unroll
  for (int m = 0; m < 2; ++m)
#pragma unroll
    for (int n = 0; n < 2; ++n) {
      int col = (nb * 8 + w * 2 + n) * 16 + lr;
#pragma unroll
      for (int r = 0; r < 4; ++r) {
        int row = mb * 32 + m * 16 + lg * 4 + r;
        zx[(size_t)row * 2048 + col] = acc[m][n][r] + bg[col];
      }
    }
}

// ---------- epoch-broadcast grid barrier (32 blocks, read-only polling) ----------
static __device__ __forceinline__ void gbar32(unsigned* ctr, unsigned* go, unsigned ep) {
  __syncthreads();
  if (threadIdx.x == 0) {
    __threadfence();  // release h writes device-wide
    unsigned prev = __hip_atomic_fetch_add(ctr, 1u, __ATOMIC_ACQ_REL, __HIP_MEMORY_SCOPE_AGENT);
    if (prev == ep * 32u + 31u) {
      __hip_atomic_store(go, ep + 1u, __ATOMIC_RELEASE, __HIP_MEMORY_SCOPE_AGENT);
    } else {
      while (__hip_atomic_load(go, __ATOMIC_ACQUIRE, __HIP_MEMORY_SCOPE_AGENT) < ep + 1u)
        __builtin_amdgcn_s_sleep(1);
    }
  }
  __syncthreads();
  __threadfence();  // acquire side: discard stale cached lines
}

// ---------- persistent LSTM: 32 blocks x 512 threads ----------
__global__ __launch_bounds__(512, 1) void k_lstm(
    const float* __restrict__ feat, const float* __restrict__ bg,
    const float* __restrict__ zx,
    const unsigned short* __restrict__ Vh, const unsigned short* __restrict__ Vl,
    unsigned short* __restrict__ hAh, unsigned short* __restrict__ hAl,
    unsigned short* __restrict__ hBh, unsigned short* __restrict__ hBl,
    unsigned short* __restrict__ hsb, float* __restrict__ hout,
    float* __restrict__ cout_, unsigned* __restrict__ barctr) {
  __shared__ float zsh[4][32][17];
  int nb = blockIdx.x;            // 32 blocks: 16-col slice of each gate
  int tid = threadIdx.x;
  int w = tid >> 6, l = tid & 63, lr = l & 15, lg = l >> 4;
  int rt = w >> 2, g = w & 3;     // wave: batch-half rt, gate g
  int n16v = g * 32 + nb;
  unsigned* ctr = barctr;
  unsigned* go = barctr + 32;     // separate 128B line
  // V fragments in registers for the whole recurrence (32x short8 = 128 VGPR)
  short8 vh[16], vl[16];
#pragma unroll
  for (int kk = 0; kk < 16; ++kk) {
    size_t bo = ((size_t)(n16v * 16 + kk) * 64 + l) * 8;
    vh[kk] = *(const short8*)(Vh + bo);
    vl[kk] = *(const short8*)(Vl + bo);
  }
  int b = tid >> 4, j = tid & 15;
  int col = nb * 16 + j;
  int ci = b * HD + col;
  // image step (h=0, c=0): z = feat broadcast to all gates + bg
  float fv = feat[ci];
  float c = sigf(fv + bg[col]) * tanh_(fv + bg[1024 + col]);
  float h = sigf(fv + bg[1536 + col]) * tanh_(c);
  {
    unsigned short hb_ = f2bf(h);
    hAh[ci] = hb_;
    hAl[ci] = f2bf(h - bf2f(hb_));
  }
  gbar32(ctr, go, 0u);
  for (int t = 0; t < 48; ++t) {
    const unsigned short* ih = (t & 1) ? hBh : hAh;
    const unsigned short* il = (t & 1) ? hBl : hAl;
    unsigned short* oh = (t & 1) ? hAh : hBh;
    unsigned short* ol = (t & 1) ? hAl : hBl;
    // prefetch zx early
    const float* zr = zx + ((size_t)t * 32 + b) * 2048 + col;
    float z0p = zr[0], z1p = zr[512], z2p = zr[1024], z3p = zr[1536];
    // z-tile = h @ V (split-bf16, 3 terms), 2 acc chains
    f32x4 acc0 = {}, acc1 = {};
#pragma unroll
    for (int kk = 0; kk < 16; ++kk) {
      size_t ao = (size_t)(rt * 16 + lr) * HD + kk * 32 + lg * 8;
      short8 ah = *(const short8*)(ih + ao);
      short8 al = *(const short8*)(il + ao);
      if (kk & 1) {
        acc1 = MFMA(ah, vh[kk], acc1);
        acc1 = MFMA(al, vh[kk], acc1);
        acc1 = MFMA(ah, vl[kk], acc1);
      } else {
        acc0 = MFMA(ah, vh[kk], acc0);
        acc0 = MFMA(al, vh[kk], acc0);
        acc0 = MFMA(ah, vl[kk], acc0);
      }
    }
#pragma unroll
    for (int r = 0; r < 4; ++r) zsh[g][rt * 16 + lg * 4 + r][lr] = acc0[r] + acc1[r];
    __syncthreads();
    float zi = zsh[0][b][j] + z0p;
    float zf = zsh[1][b][j] + z1p;
    float zg = zsh[2][b][j] + z2p;
    float zo = zsh[3][b][j] + z3p;
    c = sigf(zf) * c + sigf(zi) * tanh_(zg);
    h = sigf(zo) * tanh_(c);
    unsigned short hb2 = f2bf(h);
    oh[ci] = hb2;
    ol[ci] = f2bf(h - bf2f(hb2));
    hsb[((size_t)b * SEQ + t) * HD + col] = hb2;
    if (t < 47) gbar32(ctr, go, (unsigned)(t + 1));
  }
  hout[ci] = h;
  cout_[ci] = c;
}

// ---------- one-pass output GEMM: exp(logits) -> bf16 expb + fp32 rowsum ----------
__global__ __launch_bounds__(256, 2) void k_oute(const unsigned short* __restrict__ Af,
                                                 const unsigned short* __restrict__ Wp,
                                                 const float* __restrict__ bout,
                                                 float* __restrict__ rowsum,
                                                 unsigned short* __restrict__ expb) {
  int mb = blockIdx.x;  // 0..11  (m-tile 128)
  int nb = blockIdx.y;  // 0..127 (n-tile 256)
  int tid = threadIdx.x;
  int w = tid >> 6, l = tid & 63, lr = l & 15, lg = l >> 4;
  int wr = w >> 1, wc = w & 1;  // 2x2 waves; wave tile 64 rows x 128 cols
  int mrow0 = mb * 128 + wr * 64;
  int m16_0 = mrow0 >> 4;
  int n16_0 = nb * 16 + wc * 8;
  const short8* As = (const short8*)Af;
  const short8* Bs = (const short8*)Wp;
  f32x4 acc[4][8] = {};
  short8 bcur[8], bnxt[8];
#pragma unroll
  for (int nt = 0; nt < 8; ++nt) bcur[nt] = Bs[((n16_0 + nt) * 16 + 0) * 64 + l];
#pragma unroll
  for (int kk = 0; kk < 16; ++kk) {
    short8 a[4];
#pragma unroll
    for (int mt = 0; mt < 4; ++mt) a[mt] = As[((m16_0 + mt) * 16 + kk) * 64 + l];
    if (kk < 15) {
#pragma unroll
      for (int nt = 0; nt < 8; ++nt) bnxt[nt] = Bs[((n16_0 + nt) * 16 + kk + 1) * 64 + l];
    }
#pragma unroll
    for (int nt = 0; nt < 8; ++nt)
#pragma unroll
      for (int mt = 0; mt < 4; ++mt) acc[mt][nt] = MFMA(a[mt], bcur[nt], acc[mt][nt]);
#pragma unroll
    for (int nt = 0; nt < 8; ++nt) bcur[nt] = bnxt[nt];
  }
#pragma unroll
  for (int mt = 0; mt < 4; ++mt) {
#pragma unroll
    for (int r = 0; r < 4; ++r) {
      int row = mrow0 + mt * 16 + lg * 4 + r;
      float s = 0.f;
#pragma unroll
      for (int nt = 0; nt < 8; ++nt) {
        int col = (n16_0 + nt) * 16 + lr;
        bool valid = col < VOCAB;
        float e = __expf(acc[mt][nt][r] + (valid ? bout[col] : 0.f));
        if (valid) {
          s += e;
          expb[(size_t)row * VOCAB + col] = f2bf(e);
        }
      }
      s += __shfl_xor(s, 1);
      s += __shfl_xor(s, 2);
      s += __shfl_xor(s, 4);
      s += __shfl_xor(s, 8);
      if (lr == 0) atomicAdd(&rowsum[row], s);
    }
  }
}

// ---------- divide: out = bf2f(expb) / rowsum[row] ----------
__global__ __launch_bounds__(256) void k_div(const unsigned short* __restrict__ expb,
                                             const float* __restrict__ rowsum,
                                             float* __restrict__ out) {
  unsigned i8 = (blockIdx.x * 256u + threadIdx.x) * 8u;
  if (i8 >= 49964544u) return;
  short8 e = *(const short8*)(expb + i8);
  unsigned r0 = i8 / (unsigned)VOCAB;
  unsigned r7 = (i8 + 7u) / (unsigned)VOCAB;
  float o[8];
  if (r0 == r7) {
    float inv = 1.f / rowsum[r0];
#pragma unroll
    for (int i = 0; i < 8; ++i) o[i] = bf2f((unsigned short)e[i]) * inv;
  } else {
#pragma unroll
    for (int i = 0; i < 8; ++i) {
      unsigned rr = (i8 + i) / (unsigned)VOCAB;
      o[i] = bf2f((unsigned short)e[i]) / rowsum[rr];
    }
  }
  float4 o0 = {o[0], o[1], o[2], o[3]};
  float4 o1 = {o[4], o[5], o[6], o[7]};
  *(float4*)(out + i8) = o0;
  *(float4*)(out + i8 + 4) = o1;
}

extern "C" void kernel_launch(void* const* d_in, const int* in_sizes, int n_in,
                              void* d_out, int out_size, void* d_ws, size_t ws_size,
                              hipStream_t stream) {
  const float* img  = (const float*)d_in[0];
  const int*   x    = (const int*)d_in[1];
  const float* w1   = (const float*)d_in[2];
  const float* g1   = (const float*)d_in[4];
  const float* be1  = (const float*)d_in[5];
  const float* w2   = (const float*)d_in[6];
  const float* g2   = (const float*)d_in[8];
  const float* be2  = (const float*)d_in[9];
  const float* w3   = (const float*)d_in[10];
  const float* g3   = (const float*)d_in[12];
  const float* be3  = (const float*)d_in[13];
  const float* U    = (const float*)d_in[14];
  const float* V    = (const float*)d_in[15];
  const float* bg   = (const float*)d_in[16];
  const float* emb  = (const float*)d_in[17];
  const float* Wout = (const float*)d_in[18];
  const float* bout = (const float*)d_in[19];

  char* ws = (char*)d_ws;
  size_t off = 0;
  auto alloc = [&](size_t bytes) -> void* {
    void* p = ws + off;
    off = (off + bytes + 255) & ~(size_t)255;
    return p;
  };
  float* zx = (float*)alloc((size_t)48 * 32 * 2048 * 4);
  unsigned short* xh = (unsigned short*)alloc((size_t)1536 * 512 * 2);
  unsigned short* xl = (unsigned short*)alloc((size_t)1536 * 512 * 2);
  unsigned short* Uh = (unsigned short*)alloc((size_t)512 * 2048 * 2);
  unsigned short* Ul = (unsigned short*)alloc((size_t)512 * 2048 * 2);
  unsigned short* Vh = (unsigned short*)alloc((size_t)512 * 2048 * 2);
  unsigned short* Vl = (unsigned short*)alloc((size_t)512 * 2048 * 2);
  unsigned short* Wp = (unsigned short*)alloc((size_t)NPAD16 * 16 * 64 * 8 * 2);  // 33.6 MB
  unsigned short* Af = (unsigned short*)alloc((size_t)96 * 16 * 64 * 8 * 2);      // 1.6 MB
  unsigned short* hAh = (unsigned short*)alloc(32 * 512 * 2);
  unsigned short* hAl = (unsigned short*)alloc(32 * 512 * 2);
  unsigned short* hBh = (unsigned short*)alloc(32 * 512 * 2);
  unsigned short* hBl = (unsigned short*)alloc(32 * 512 * 2);
  unsigned short* hsb = (unsigned short*)alloc((size_t)1536 * 512 * 2);
  float* feat = (float*)alloc(32 * 512 * 4);
  float* h1 = (float*)alloc(32 * 2048 * 4);
  float* h2 = (float*)alloc(32 * 1024 * 4);
  float* rowsum = (float*)alloc(1536 * 4);
  unsigned* barctr = (unsigned*)alloc(512);
  unsigned short* expb = (unsigned short*)alloc((size_t)49964544 * 2);  // 100 MB

  float* out = (float*)d_out;
  float* hout = out + 49964544;
  float* cout_ = out + 49964544 + 16384;

  k_gather<<<dim3(768), dim3(256), 0, stream>>>(emb, x, xh, xl);
  k_pack<<<dim3(512), dim3(256), 0, stream>>>(U, Uh, Ul);
  k_pack<<<dim3(512), dim3(256), 0, stream>>>(V, Vh, Vl);
  k_packw<<<dim3(8192), dim3(256), 0, stream>>>(Wout, Wp);
  k_cnn<4096, 2048><<<dim3(256), dim3(256), 0, stream>>>(img, w1, g1, be1, h1);
  k_cnn<2048, 1024><<<dim3(128), dim3(256), 0, stream>>>(h1, w2, g2, be2, h2);
  k_cnn<1024, 512><<<dim3(64), dim3(256), 0, stream>>>(h2, w3, g3, be3, feat);
  k_xu<<<dim3(48, 16), dim3(256), 0, stream>>>(xh, xl, Uh, Ul, bg, zx);
  hipMemsetAsync(barctr, 0, 512, stream);
  hipMemsetAsync(rowsum, 0, 1536 * 4, stream);
  k_lstm<<<dim3(32), dim3(512), 0, stream>>>(feat, bg, zx, Vh, Vl, hAh, hAl, hBh, hBl,
                                             hsb, hout, cout_, barctr);
  k_packa<<<dim3(384), dim3(256), 0, stream>>>(hsb, Af);
  k_oute<<<dim3(12, 128), dim3(256), 0, stream>>>(Af, Wp, bout, rowsum, expb);
  k_div<<<dim3(24397), dim3(256), 0, stream>>>(expb, rowsum, out);
}